// Round 4
// baseline (366.025 us; speedup 1.0000x reference)
//
#include <hip/hip_runtime.h>
#include <hip/hip_bf16.h>

// GCN: 2x GCNConv(128->128) + LeakyReLU(0.1) + mean over channels.
// N=50000, E=1600000, D=128, fp32 in/out.
//
// R13: build-phase collapse. R12 lesson: 4-slot batched gather wastes ~35%
//   ACC8 work on Poisson tails -> gather reverted to R9b 2-deep verbatim.
//   Bucket+counting-sort machinery (hist/scan/scatter/sort, ~43us + 3
//   boundaries) replaced by direct per-node counting sort:
//   M0: graph memset zeroes row counts + tickets.
//   L1 degscan: 391 deg blocks (global atomicAdd, device-coherent) -> ticket;
//       196 scan blocks spin, atomic-read counts, tile scan + totals scan
//       (2nd ticket) -> absolute row, cur, dinv. Atomics make intra-kernel
//       ticket/spin safe across XCDs (same pattern as R9b K2); 588 light
//       blocks trivially co-resident (no LDS-heavy branch may spin: gemm
//       34.8KB LDS would cap 4 blocks/CU -> deadlock; gemm stays spin-free).
//   L2 scattergemm: 391 scatter blocks (slot=atomicAdd(&cur[d],1)) || 782
//       MFMA gemm blocks (R9b K4 gemm verbatim; drain-scheduled, no spin).
//   L3 gather (R9b verbatim), L4 out (R9b verbatim).
// Math (verified R2-R8): h[u]=bf16((x@W1)[u]);  g UNSCALED, dinv per-edge fma:
//   mg[u]=dinv[u]*dot(lrelu(dinv[u]*sum_{n in N(u)+u} dinv[n]*h[n] + b1), mean_j W2[:,j]);
//   out[v]=dinv[v]*(mg[v]+sum mg[nbr]) + mean(b2).

#define N_NODES 50000
#define NPAD 50048
#define D 128
#define CHUNK 4096       // edges per deg/scatter block
#define WT_STRIDE 136

typedef unsigned int uint;
typedef unsigned short u16;
typedef __attribute__((ext_vector_type(8))) short short8;   // 8 bf16 (4 VGPRs)
typedef __attribute__((ext_vector_type(4))) float floatx4;

__device__ __forceinline__ u16 cvt_bf16(float f) {
    uint u = __float_as_uint(f);
    return (u16)((u + 0x7fffu + ((u >> 16) & 1u)) >> 16);   // RNE
}
__device__ __forceinline__ uint pack_bf2(float a, float b) {
    return (uint)cvt_bf16(a) | ((uint)cvt_bf16(b) << 16);
}

// ---------------- L1: degree count -> ticket -> tile scan -> totals -> row/cur/dinv ----------------
// Blocks [0,CHN): per-chunk atomicAdd(&row[dst],1). Block CHN: w2m. Blocks
// [CHN+1, CHN+1+NSB): spin until deg done, then scan. All cross-phase data
// moves through device-scope atomics (coherent across the 8 XCD L2s).
__global__ __launch_bounds__(256) void degscan_kernel(
    const int* __restrict__ dst, const float* __restrict__ W2,
    const float* __restrict__ b2, float* __restrict__ w2m,
    int* __restrict__ row, uint* __restrict__ cnt, uint* __restrict__ T,
    float* __restrict__ dinv, uint* __restrict__ cur,
    int E, int CHN, int N) {
    int t = threadIdx.x, c = blockIdx.x;
    uint* rowu = (uint*)row;

    if (c < CHN) {                         // ---- degree count ----
        int e0 = c * CHUNK;
        for (int i = t; i < CHUNK; i += 256) {
            int e = e0 + i;
            if (e < E) atomicAdd(&rowu[dst[e]], 1u);
        }
        __threadfence();
        __syncthreads();                   // barrier drains vmcnt -> atomics performed
        if (t == 0) atomicAdd(&cnt[0], 1u);
    } else if (c == CHN) {                 // ---- w2m ----
        if (t < 128) {
            float s = 0.f;
            for (int j = 0; j < 128; j++) s += W2[t * 128 + j];
            w2m[t] = s * (1.0f / 128.0f);
        } else if (t == 128) {
            float s = 0.f;
            for (int j = 0; j < 128; j++) s += b2[j];
            w2m[128] = s * (1.0f / 128.0f);
        }
    } else {                               // ---- scan (NSB = gridDim-CHN-1 blocks) ----
        __shared__ uint s[256];
        __shared__ uint Bb_sh;
        int NSB = (int)gridDim.x - CHN - 1;
        int b = c - CHN - 1;
        if (t == 0) {                      // wait for all deg blocks
            while (atomicAdd(&cnt[0], 0u) < (uint)CHN) __builtin_amdgcn_s_sleep(8);
        }
        __syncthreads();
        int v = b * 256 + t;
        uint cv = (v < N) ? atomicAdd(&rowu[v], 0u) : 0u;   // coherent read of count
        s[t] = cv;
        __syncthreads();
#pragma unroll
        for (int off = 1; off < 256; off <<= 1) {
            uint u = (t >= off) ? s[t - off] : 0u;
            __syncthreads();
            s[t] += u;
            __syncthreads();
        }
        uint excl = s[t] - cv;             // exclusive prefix within tile
        if (t == 0) {
            atomicExch(&T[b], s[255]);     // tile total, device scope
            __threadfence();
            atomicAdd(&cnt[1], 1u);
            while (atomicAdd(&cnt[1], 0u) < (uint)NSB) __builtin_amdgcn_s_sleep(8);
        }
        __syncthreads();
        uint tv = (t < NSB) ? atomicAdd(&T[t], 0u) : 0u;    // coherent totals
        s[t] = tv;
        __syncthreads();
#pragma unroll
        for (int off = 1; off < 256; off <<= 1) {
            uint u = (t >= off) ? s[t - off] : 0u;
            __syncthreads();
            s[t] += u;
            __syncthreads();
        }
        if (t == b) Bb_sh = s[t] - tv;     // exclusive tile offset for this block
        __syncthreads();
        uint base = Bb_sh;
        if (v < N) {
            uint r = base + excl;
            row[v] = (int)r;               // plain stores: read next launch
            cur[v] = r;
            dinv[v] = rsqrtf((float)(cv + 1u));   // +1 self-loop
        }
        if (b == 0 && t == 0) row[N] = E;
    }
}

// ---------------- L2: scatter (blocks 0..CHN-1)  ||  MFMA gemm (blocks CHN..) ----------------
// Scatter: esrc[atomicAdd(&cur[dst],1)] = src  (grouped by dst, order-free).
// Gemm: g16[M,128] = bf16( x @ W1 )  -- UNSCALED (dinv applied per-edge in gather).
__global__ __launch_bounds__(256) void scattergemm_kernel(
    const int* __restrict__ src, const int* __restrict__ dst,
    uint* __restrict__ cur, u16* __restrict__ esrc,
    const float* __restrict__ A, const float* __restrict__ W,
    uint* __restrict__ G32, int E, int CHN, int M) {
    __shared__ u16 wt[128 * WT_STRIDE];    // 34.8 KB (gemm branch only)
    int t = threadIdx.x;

    if (blockIdx.x < (uint)CHN) {          // ---- scatter ----
        int e0 = blockIdx.x * CHUNK;
        for (int i = t; i < CHUNK; i += 256) {
            int e = e0 + i;
            if (e < E) {
                int d = dst[e];
                uint slot = atomicAdd(&cur[d], 1u);
                esrc[slot] = (u16)src[e];  // N < 65536 -> src fits u16
            }
        }
    } else {                               // ---- MFMA gemm ----
        int bid = blockIdx.x - CHN;
        for (int i = t; i < 128 * 128; i += 256) {   // stage W1^T as bf16
            int k = i >> 7, n = i & 127;
            wt[n * WT_STRIDE + k] = cvt_bf16(W[i]);
        }
        __syncthreads();

        int wave = t >> 6, lane = t & 63;
        int m = lane & 15, quad = lane >> 4;
        int rowa = bid * 64 + wave * 16 + m;
        int rowc = rowa < M ? rowa : M - 1;
        const float* Arow = A + (long)rowc * D;

        short8 afrag[4];
#pragma unroll
        for (int kt = 0; kt < 4; kt++) {
            int k0 = kt * 32 + quad * 8;
            float4 f0 = *(const float4*)(Arow + k0);
            float4 f1 = *(const float4*)(Arow + k0 + 4);
            short8 af;
            af[0] = (short)cvt_bf16(f0.x); af[1] = (short)cvt_bf16(f0.y);
            af[2] = (short)cvt_bf16(f0.z); af[3] = (short)cvt_bf16(f0.w);
            af[4] = (short)cvt_bf16(f1.x); af[5] = (short)cvt_bf16(f1.y);
            af[6] = (short)cvt_bf16(f1.z); af[7] = (short)cvt_bf16(f1.w);
            afrag[kt] = af;
        }

        int orow0 = bid * 64 + wave * 16;
        for (int n0 = 0; n0 < 128; n0 += 16) {
            floatx4 acc = {0.f, 0.f, 0.f, 0.f};
#pragma unroll
            for (int kt = 0; kt < 4; kt++) {
                short8 bf = *(const short8*)(wt + (n0 + m) * WT_STRIDE + kt * 32 + quad * 8);
                acc = __builtin_amdgcn_mfma_f32_16x16x32_bf16(afrag[kt], bf, acc, 0, 0, 0);
            }
#pragma unroll
            for (int r = 0; r < 4; r++) {
                float val = acc[r];
                float oth = __shfl_xor(val, 1, 64);      // partner column
                int orow = orow0 + quad * 4 + r;
                if (orow < M && (m & 1) == 0)
                    G32[(long)orow * 64 + ((n0 + m) >> 1)] = pack_bf2(val, oth);
            }
        }
    }
}

// ---------------- L3: fused gather(bf16, dinv-fma) + leakyrelu + dot(w2m) ----------------
// R9b verbatim: one wave/node; 8 chains x 8 lanes; 2 uint4/edge, 2-deep pipeline.
// dinv[src] applied per edge via fma (g is unscaled).
__global__ __launch_bounds__(256) void gather_node_kernel(
    const int* __restrict__ row, const u16* __restrict__ esrc,
    const uint* __restrict__ g16, const float* __restrict__ dinv,
    const float* __restrict__ b1, const float* __restrict__ w2m,
    float* __restrict__ mg, int N) {
    int wave = threadIdx.x >> 6;
    int lane = threadIdx.x & 63;
    int sub = lane & 7;        // 16-channel slice: uint4 pair 2*sub, 2*sub+1
    int nb = lane >> 3;        // 8 neighbor chains
    int v = blockIdx.x * 4 + wave;
    if (v >= N) return;

    const uint4* gv = (const uint4*)g16;   // 16 uint4 per 256B row
    float dvv = dinv[v];
    float acc[16];
#pragma unroll
    for (int i = 0; i < 16; i++) acc[i] = 0.f;

#define ACC8(ua, ub, wgt) {                                              \
    uint uu[8] = {(ua).x, (ua).y, (ua).z, (ua).w, (ub).x, (ub).y, (ub).z, (ub).w}; \
    _Pragma("unroll")                                                    \
    for (int i = 0; i < 8; i++) {                                        \
        acc[2*i]   += (wgt) * __uint_as_float(uu[i] << 16);              \
        acc[2*i+1] += (wgt) * __uint_as_float(uu[i] & 0xffff0000u);      \
    } }

    if (nb == 0) {             // self-loop term: dinv[v]*h[v]
        long rb = (long)v * 16 + 2 * sub;
        uint4 ua = gv[rb], ub = gv[rb + 1];
        ACC8(ua, ub, dvv)
    }
    int jb = row[v], je = row[v + 1];
    int j = jb + nb;
    if (j < je) {              // 2-deep pipeline per chain
        int s0 = esrc[j];
        float wA = dinv[s0];
        long r0 = (long)s0 * 16 + 2 * sub;
        uint4 p0 = gv[r0], p1 = gv[r0 + 1];
        j += 8;
        while (j < je) {
            int s1 = esrc[j];
            float wB = dinv[s1];
            long r1 = (long)s1 * 16 + 2 * sub;
            uint4 q0 = gv[r1], q1 = gv[r1 + 1];
            j += 8;
            ACC8(p0, p1, wA)
            p0 = q0; p1 = q1; wA = wB;
        }
        ACC8(p0, p1, wA)
    }
#undef ACC8

    // reduce the 8 chains
#pragma unroll
    for (int i = 0; i < 16; i++) {
        acc[i] += __shfl_xor(acc[i], 8, 64);
        acc[i] += __shfl_xor(acc[i], 16, 64);
        acc[i] += __shfl_xor(acc[i], 32, 64);
    }

    if (nb == 0) {             // lane sub holds channels 16*sub .. 16*sub+15
        const float4* bp = (const float4*)b1;
        const float4* wp = (const float4*)w2m;
        float s = 0.f;
#pragma unroll
        for (int q4 = 0; q4 < 4; q4++) {
            float4 bb = bp[sub * 4 + q4];
            float4 wm = wp[sub * 4 + q4];
            float t0 = dvv * acc[4*q4 + 0] + bb.x; t0 = t0 >= 0.f ? t0 : 0.1f * t0;
            float t1 = dvv * acc[4*q4 + 1] + bb.y; t1 = t1 >= 0.f ? t1 : 0.1f * t1;
            float t2 = dvv * acc[4*q4 + 2] + bb.z; t2 = t2 >= 0.f ? t2 : 0.1f * t2;
            float t3 = dvv * acc[4*q4 + 3] + bb.w; t3 = t3 >= 0.f ? t3 : 0.1f * t3;
            s += t0 * wm.x + t1 * wm.y + t2 * wm.z + t3 * wm.w;
        }
        s += __shfl_xor(s, 1, 64);
        s += __shfl_xor(s, 2, 64);
        s += __shfl_xor(s, 4, 64);
        if (sub == 0) mg[v] = dvv * s;
    }
}

// ---------------- L4: scalar aggregate for conv2 + mean ----------------
__global__ void out_kernel(const int* __restrict__ row, const u16* __restrict__ esrc,
                           const float* __restrict__ mg, const float* __restrict__ dinv,
                           const float* __restrict__ w2m, float* __restrict__ out, int N) {
    int v = blockIdx.x * blockDim.x + threadIdx.x;
    if (v >= N) return;
    float acc = mg[v];
    int jb = row[v], je = row[v + 1];
    int j = jb;
    for (; j + 8 <= je; j += 8) {
        acc += mg[esrc[j]] + mg[esrc[j + 1]] + mg[esrc[j + 2]] + mg[esrc[j + 3]] +
               mg[esrc[j + 4]] + mg[esrc[j + 5]] + mg[esrc[j + 6]] + mg[esrc[j + 7]];
    }
    for (; j < je; j++) acc += mg[esrc[j]];
    out[v] = dinv[v] * acc + w2m[128];
}

extern "C" void kernel_launch(void* const* d_in, const int* in_sizes, int n_in,
                              void* d_out, int out_size, void* d_ws, size_t ws_size,
                              hipStream_t stream) {
    const float* x  = (const float*)d_in[0];
    const int* ei   = (const int*)d_in[1];
    const float* W1 = (const float*)d_in[2];
    const float* b1 = (const float*)d_in[3];
    const float* W2 = (const float*)d_in[4];
    const float* b2 = (const float*)d_in[5];
    float* out = (float*)d_out;

    const int N = N_NODES;
    const int E = in_sizes[1] / 2;
    const int* src = ei;
    const int* dst = ei + E;
    const int CHN = (E + CHUNK - 1) / CHUNK;   // 391
    const int NSB = (N + 255) / 256;           // 196 scan tiles / out blocks
    const int GB  = (N + 63) / 64;             // 782 gemm blocks

    // workspace (4B units)
    float*    dinv = (float*)d_ws;                        // [NPAD]
    int*      row  = (int*)(dinv + NPAD);                 // [NPAD+16]; counters at +NPAD
    uint*     cnt  = (uint*)(row + NPAD);                 // [2] tickets (inside row pad)
    uint*     T    = (uint*)(row + NPAD + 16);            // [256] tile totals
    float*    w2m  = (float*)(T + 256);                   // [256] ([128]=mean b2)
    float*    mg   = w2m + 256;                           // [NPAD]
    uint*     cur  = (uint*)(mg + NPAD);                  // [NPAD] scatter cursors
    uint*     g16u = cur + NPAD;                          // [NPAD*64] (16B aligned)
    u16*      esrc = (u16*)(g16u + (long)NPAD * 64);      // [E] u16

    // M0: zero per-node counts row[0..N] + tickets cnt[0..1] (graph memset node)
    hipMemsetAsync(row, 0, (size_t)(NPAD + 2) * sizeof(int), stream);

    // L1: deg count (391) + w2m (1) -> ticket -> scan (196): row/cur/dinv
    degscan_kernel<<<CHN + 1 + NSB, 256, 0, stream>>>(dst, W2, b2, w2m,
                                                      row, cnt, T, dinv, cur, E, CHN, N);
    // L2: scatter (391) || MFMA gemm (782)
    scattergemm_kernel<<<CHN + GB, 256, 0, stream>>>(src, dst, cur, esrc,
                                                     x, W1, g16u, E, CHN, N);
    // L3: gather + lrelu + dot -> mg
    gather_node_kernel<<<(N + 3) / 4, 256, 0, stream>>>(row, esrc, g16u, dinv, b1, w2m, mg, N);
    // L4: scalar aggregate + mean -> out
    out_kernel<<<NSB, 256, 0, stream>>>(row, esrc, mg, dinv, w2m, out, N);
}

// Round 5
// 202.188 us; speedup vs baseline: 1.8103x; 1.8103x over previous
//
#include <hip/hip_runtime.h>
#include <hip/hip_bf16.h>

// GCN: 2x GCNConv(128->128) + LeakyReLU(0.1) + mean over channels.
// N=50000, E=1600000, D=128, fp32 in/out.
//
// R14: R9b 6-kernel structure (196-198us known-good anchor). Cross-block-sync
//   ladder is now fully explored and DEAD: grid.sync ~45us each (R11);
//   RMW-atomic spin catastrophic (R13: 130us, WRITE 50MB = 12.5M spin-RMWs
//   ping-ponging one line across 8 XCDs, serializing all kernel atomics).
//   Only validated pattern: R9b K2's spin-free last-ticket-does-serial-step.
// Two in-place changes vs R9b:
//   K4 gemm: 64 -> 128 rows/block (391 blocks). W1-staging (64KB + 16K
//     cvt/ds_write per block) was ~50% of gemm cost at 782 blocks; amortize 2x.
//   K5 gather: 2 edges per iteration, 2-pair pipeline (4 rows in flight,
//     ~160cy latency cover vs 80cy at 2-deep). Zero wasted ACC8s (R12 lesson:
//     batched tails cost 35% extra VALU): in-loop slots provably valid
//     (loop-continue implies D valid), only final drain B is predicated.
// Math (verified R2-R8): h[u]=bf16((x@W1)[u]);  g UNSCALED, dinv per-edge fma:
//   mg[u]=dinv[u]*dot(lrelu(dinv[u]*sum_{n in N(u)+u} dinv[n]*h[n] + b1), mean_j W2[:,j]);
//   out[v]=dinv[v]*(mg[v]+sum mg[nbr]) + mean(b2).

#define N_NODES 50000
#define NPAD 50048
#define D 128
#define BK 196           // node buckets: v>>8
#define CHUNK 4096       // edges per stage-1 block

typedef unsigned int uint;
typedef unsigned short u16;
typedef __attribute__((ext_vector_type(8))) short short8;   // 8 bf16 (4 VGPRs)
typedef __attribute__((ext_vector_type(4))) float floatx4;

__device__ __forceinline__ u16 cvt_bf16(float f) {
    uint u = __float_as_uint(f);
    return (u16)((u + 0x7fffu + ((u >> 16) & 1u)) >> 16);   // RNE
}
__device__ __forceinline__ uint pack_bf2(float a, float b) {
    return (uint)cvt_bf16(a) | ((uint)cvt_bf16(b) << 16);
}

// ---------------- K1: per-chunk bucket histogram  +  w2m  +  counter init ----------------
__global__ void hist_w2m_kernel(const int* __restrict__ dst, uint* __restrict__ H,
                                const float* __restrict__ W2, const float* __restrict__ b2,
                                float* __restrict__ w2m, uint* __restrict__ counter,
                                int E, int CHN) {
    int t = threadIdx.x, c = blockIdx.x;
    if (c < CHN) {                         // histogram chunk
        __shared__ uint h[BK];
        if (t < BK) h[t] = 0;
        __syncthreads();
        int e0 = c * CHUNK;
        for (int i = t; i < CHUNK; i += 256) {
            int e = e0 + i;
            if (e < E) atomicAdd(&h[dst[e] >> 8], 1u);
        }
        __syncthreads();
        if (t < BK) H[t * CHN + c] = h[t]; // bucket-major for column scan
    } else {                               // w2m block
        if (t < 128) {
            float s = 0.f;
            for (int j = 0; j < 128; j++) s += W2[t * 128 + j];
            w2m[t] = s * (1.0f / 128.0f);
        } else if (t == 128) {
            float s = 0.f;
            for (int j = 0; j < 128; j++) s += b2[j];
            w2m[128] = s * (1.0f / 128.0f);
        } else if (t == 129) {
            *counter = 0;                  // for K2 last-block detection
        }
    }
}

// ---------------- K2: per-bucket scan over chunks; last block scans totals ----------------
__global__ void scan_kernel(uint* __restrict__ H, uint* __restrict__ T, uint* __restrict__ B,
                            int* __restrict__ row, uint* __restrict__ counter,
                            int CHN, int E, int N) {
    __shared__ uint s[256];
    __shared__ uint ticket_sh;
    int t = threadIdx.x, b = blockIdx.x;
    uint carry = 0;
    for (int base = 0; base < CHN; base += 256) {
        int idx = base + t;
        uint v = (idx < CHN) ? H[b * CHN + idx] : 0u;
        s[t] = v;
        __syncthreads();
#pragma unroll
        for (int off = 1; off < 256; off <<= 1) {
            uint u = (t >= off) ? s[t - off] : 0u;
            __syncthreads();
            s[t] += u;
            __syncthreads();
        }
        if (idx < CHN) H[b * CHN + idx] = carry + s[t] - v;   // exclusive + carry
        carry += s[255];
        __syncthreads();
    }
    if (t == 0) {
        atomicExch(&T[b], carry);          // device-scope store (crosses XCD L2s)
        __threadfence();
        ticket_sh = atomicAdd(counter, 1);
    }
    __syncthreads();
    if (ticket_sh == (uint)(gridDim.x - 1)) {      // last block: scan bucket totals
        __threadfence();
        uint v = (t < BK) ? atomicAdd(&T[t], 0u) : 0u;   // atomic read (coherent)
        s[t] = v;
        __syncthreads();
#pragma unroll
        for (int off = 1; off < 256; off <<= 1) {
            uint u = (t >= off) ? s[t - off] : 0u;
            __syncthreads();
            s[t] += u;
            __syncthreads();
        }
        if (t < BK) B[t] = s[t] - v;
        if (t == 0) { B[BK] = (uint)E; row[N] = E; }
    }
}

// ---------------- K3: scatter edges into bucket regions (LDS cursors) ----------------
__global__ void scatter_kernel(const int* __restrict__ src, const int* __restrict__ dst,
                               const uint* __restrict__ H, const uint* __restrict__ B,
                               uint* __restrict__ EB, int E, int CHN) {
    __shared__ uint cur[BK];
    int t = threadIdx.x, c = blockIdx.x;
    if (t < BK) cur[t] = B[t] + H[t * CHN + c];
    __syncthreads();
    int e0 = c * CHUNK;
    for (int i = t; i < CHUNK; i += 256) {
        int e = e0 + i;
        if (e < E) {
            int d = dst[e];
            uint slot = atomicAdd(&cur[d >> 8], 1u);
            EB[slot] = ((uint)(d & 255) << 16) | (uint)src[e];
        }
    }
}

// ---------------- K4: bucket_sort (blocks 0..BK-1)  ||  MFMA gemm (blocks BK..) ----------------
// Sort: per-bucket counting sort by dst&255 -> esrc, row, dinv (dense writes).
// Gemm: g16[M,128] = bf16( x @ W1 )  -- UNSCALED (dinv applied per-edge in gather).
// R14: gemm does 128 rows/block (2 row-groups) to amortize the W1 LDS staging.
#define WT_STRIDE 136
union SortGemmSmem {
    struct { uint cnt[256], s[256], cur[256]; } sort;
    u16 wt[128 * WT_STRIDE];               // 34.8 KB
};
__global__ __launch_bounds__(256) void sortgemm_kernel(
    const uint* __restrict__ EB, const uint* __restrict__ B,
    int* __restrict__ row, float* __restrict__ dinv, u16* __restrict__ esrc,
    const float* __restrict__ A, const float* __restrict__ W,
    uint* __restrict__ G32, int N, int M) {
    __shared__ SortGemmSmem sm;
    int t = threadIdx.x;

    if (blockIdx.x < BK) {                 // ---- bucket sort ----
        int b = blockIdx.x;
        uint base = B[b], ne = B[b + 1] - base;
        sm.sort.cnt[t] = 0;
        __syncthreads();
        for (uint i = t; i < ne; i += 256) atomicAdd(&sm.sort.cnt[EB[base + i] >> 16], 1u);
        __syncthreads();
        uint c = sm.sort.cnt[t];
        sm.sort.s[t] = c;
        __syncthreads();
#pragma unroll
        for (int off = 1; off < 256; off <<= 1) {
            uint u = (t >= off) ? sm.sort.s[t - off] : 0u;
            __syncthreads();
            sm.sort.s[t] += u;
            __syncthreads();
        }
        uint p = sm.sort.s[t] - c;          // exclusive prefix within bucket
        int v = (b << 8) + t;
        if (v < N) {
            row[v] = (int)(base + p);
            dinv[v] = rsqrtf((float)(c + 1u));   // +1 self-loop
        }
        sm.sort.cur[t] = base + p;
        __syncthreads();
        for (uint i = t; i < ne; i += 256) {
            uint u = EB[base + i];
            uint slot = atomicAdd(&sm.sort.cur[u >> 16], 1u);
            esrc[slot] = (u16)(u & 0xffffu);
        }
    } else {                               // ---- MFMA gemm, 128 rows/block ----
        int bid = blockIdx.x - BK;
        for (int i = t; i < 128 * 128; i += 256) {   // stage W1^T as bf16 (once)
            int k = i >> 7, n = i & 127;
            sm.wt[n * WT_STRIDE + k] = cvt_bf16(W[i]);
        }
        __syncthreads();

        int wave = t >> 6, lane = t & 63;
        int m = lane & 15, quad = lane >> 4;

#pragma unroll
        for (int rg = 0; rg < 2; rg++) {
            int rowa = bid * 128 + rg * 64 + wave * 16 + m;
            int rowc = rowa < M ? rowa : M - 1;
            const float* Arow = A + (long)rowc * D;

            short8 afrag[4];
#pragma unroll
            for (int kt = 0; kt < 4; kt++) {
                int k0 = kt * 32 + quad * 8;
                float4 f0 = *(const float4*)(Arow + k0);
                float4 f1 = *(const float4*)(Arow + k0 + 4);
                short8 af;
                af[0] = (short)cvt_bf16(f0.x); af[1] = (short)cvt_bf16(f0.y);
                af[2] = (short)cvt_bf16(f0.z); af[3] = (short)cvt_bf16(f0.w);
                af[4] = (short)cvt_bf16(f1.x); af[5] = (short)cvt_bf16(f1.y);
                af[6] = (short)cvt_bf16(f1.z); af[7] = (short)cvt_bf16(f1.w);
                afrag[kt] = af;
            }

            int orow0 = bid * 128 + rg * 64 + wave * 16;
            for (int n0 = 0; n0 < 128; n0 += 16) {
                floatx4 acc = {0.f, 0.f, 0.f, 0.f};
#pragma unroll
                for (int kt = 0; kt < 4; kt++) {
                    short8 bf = *(const short8*)(sm.wt + (n0 + m) * WT_STRIDE + kt * 32 + quad * 8);
                    acc = __builtin_amdgcn_mfma_f32_16x16x32_bf16(afrag[kt], bf, acc, 0, 0, 0);
                }
#pragma unroll
                for (int r = 0; r < 4; r++) {
                    float val = acc[r];
                    float oth = __shfl_xor(val, 1, 64);      // partner column
                    int orow = orow0 + quad * 4 + r;
                    if (orow < M && (m & 1) == 0)
                        G32[(long)orow * 64 + ((n0 + m) >> 1)] = pack_bf2(val, oth);
                }
            }
        }
    }
}

// ---------------- K5: fused gather(bf16, dinv-fma) + leakyrelu + dot(w2m) ----------------
// One wave/node; 8 chains x 8 lanes; 16 channels per lane.
// R14: 2 edges/iteration, 2-pair pipeline (A,B accumulate while C,D load).
// In-loop ACCs always valid (loop-continue implies D valid); final B drain
// predicated. dinv[src] applied per edge via fma (g is unscaled).
__global__ __launch_bounds__(256) void gather_node_kernel(
    const int* __restrict__ row, const u16* __restrict__ esrc,
    const uint* __restrict__ g16, const float* __restrict__ dinv,
    const float* __restrict__ b1, const float* __restrict__ w2m,
    float* __restrict__ mg, int N) {
    int wave = threadIdx.x >> 6;
    int lane = threadIdx.x & 63;
    int sub = lane & 7;        // 16-channel slice: uint4 pair 2*sub, 2*sub+1
    int nb = lane >> 3;        // 8 neighbor chains
    int v = blockIdx.x * 4 + wave;
    if (v >= N) return;

    const uint4* gv = (const uint4*)g16;   // 16 uint4 per 256B row
    float dvv = dinv[v];
    float acc[16];
#pragma unroll
    for (int i = 0; i < 16; i++) acc[i] = 0.f;

#define ACC8(ua, ub, wgt) {                                              \
    uint uu[8] = {(ua).x, (ua).y, (ua).z, (ua).w, (ub).x, (ub).y, (ub).z, (ub).w}; \
    _Pragma("unroll")                                                    \
    for (int i = 0; i < 8; i++) {                                        \
        acc[2*i]   += (wgt) * __uint_as_float(uu[i] << 16);              \
        acc[2*i+1] += (wgt) * __uint_as_float(uu[i] & 0xffff0000u);      \
    } }

    if (nb == 0) {             // self-loop term: dinv[v]*h[v]
        long rb = (long)v * 16 + 2 * sub;
        uint4 ua = gv[rb], ub = gv[rb + 1];
        ACC8(ua, ub, dvv)
    }
    int jb = row[v], je = row[v + 1];
    int j = jb + nb;
    if (j < je) {
        // prologue: fill A, B
        int sA = esrc[j];
        float wA = dinv[sA];
        long rA = (long)sA * 16 + 2 * sub;
        uint4 a0 = gv[rA], a1 = gv[rA + 1];
        int jB = j + 8;
        bool hasB = jB < je;
        int sB = hasB ? esrc[jB] : 0;
        float wB = hasB ? dinv[sB] : 0.f;
        long rB = (long)sB * 16 + 2 * sub;
        uint4 b0 = gv[rB], b1v = gv[rB + 1];   // dummy row 0 if !hasB (never ACCed)
        int jC = jB + 8;
        while (jC < je) {      // entering implies A,B,C valid
            int sC = esrc[jC];
            int jD = jC + 8;
            bool hasD = jD < je;
            int sD = hasD ? esrc[jD] : 0;
            float wC = dinv[sC];
            float wD = hasD ? dinv[sD] : 0.f;
            long rC = (long)sC * 16 + 2 * sub;
            long rD = (long)sD * 16 + 2 * sub;
            uint4 c0 = gv[rC], c1 = gv[rC + 1];
            uint4 d0 = gv[rD], d1 = gv[rD + 1];
            jC = jD + 8;
            ACC8(a0, a1, wA)
            ACC8(b0, b1v, wB)
            a0 = c0; a1 = c1; wA = wC;
            b0 = d0; b1v = d1; wB = wD;
            hasB = hasD;       // D slot validity carries to drain
        }
        ACC8(a0, a1, wA)
        if (hasB) ACC8(b0, b1v, wB)
    }
#undef ACC8

    // reduce the 8 chains
#pragma unroll
    for (int i = 0; i < 16; i++) {
        acc[i] += __shfl_xor(acc[i], 8, 64);
        acc[i] += __shfl_xor(acc[i], 16, 64);
        acc[i] += __shfl_xor(acc[i], 32, 64);
    }

    if (nb == 0) {             // lane sub holds channels 16*sub .. 16*sub+15
        const float4* bp = (const float4*)b1;
        const float4* wp = (const float4*)w2m;
        float s = 0.f;
#pragma unroll
        for (int q4 = 0; q4 < 4; q4++) {
            float4 bb = bp[sub * 4 + q4];
            float4 wm = wp[sub * 4 + q4];
            float t0 = dvv * acc[4*q4 + 0] + bb.x; t0 = t0 >= 0.f ? t0 : 0.1f * t0;
            float t1 = dvv * acc[4*q4 + 1] + bb.y; t1 = t1 >= 0.f ? t1 : 0.1f * t1;
            float t2 = dvv * acc[4*q4 + 2] + bb.z; t2 = t2 >= 0.f ? t2 : 0.1f * t2;
            float t3 = dvv * acc[4*q4 + 3] + bb.w; t3 = t3 >= 0.f ? t3 : 0.1f * t3;
            s += t0 * wm.x + t1 * wm.y + t2 * wm.z + t3 * wm.w;
        }
        s += __shfl_xor(s, 1, 64);
        s += __shfl_xor(s, 2, 64);
        s += __shfl_xor(s, 4, 64);
        if (sub == 0) mg[v] = dvv * s;
    }
}

// ---------------- K6: scalar aggregate for conv2 + mean ----------------
__global__ void out_kernel(const int* __restrict__ row, const u16* __restrict__ esrc,
                           const float* __restrict__ mg, const float* __restrict__ dinv,
                           const float* __restrict__ w2m, float* __restrict__ out, int N) {
    int v = blockIdx.x * blockDim.x + threadIdx.x;
    if (v >= N) return;
    float acc = mg[v];
    int jb = row[v], je = row[v + 1];
    int j = jb;
    for (; j + 8 <= je; j += 8) {
        acc += mg[esrc[j]] + mg[esrc[j + 1]] + mg[esrc[j + 2]] + mg[esrc[j + 3]] +
               mg[esrc[j + 4]] + mg[esrc[j + 5]] + mg[esrc[j + 6]] + mg[esrc[j + 7]];
    }
    for (; j < je; j++) acc += mg[esrc[j]];
    out[v] = dinv[v] * acc + w2m[128];
}

extern "C" void kernel_launch(void* const* d_in, const int* in_sizes, int n_in,
                              void* d_out, int out_size, void* d_ws, size_t ws_size,
                              hipStream_t stream) {
    const float* x  = (const float*)d_in[0];
    const int* ei   = (const int*)d_in[1];
    const float* W1 = (const float*)d_in[2];
    const float* b1 = (const float*)d_in[3];
    const float* W2 = (const float*)d_in[4];
    const float* b2 = (const float*)d_in[5];
    float* out = (float*)d_out;

    const int N = N_NODES;
    const int E = in_sizes[1] / 2;
    const int* src = ei;
    const int* dst = ei + E;
    const int CHN = (E + CHUNK - 1) / CHUNK;   // 391
    const int nblocks = (N + 255) / 256;       // 196
    const int GB = (N + 127) / 128;            // 391 gemm blocks (128 rows each)

    // workspace (4B units). EB is NOT aliased with g16 (sort runs || gemm in K4).
    float*    dinv    = (float*)d_ws;                     // [NPAD]
    int*      row     = (int*)(dinv + NPAD);              // [NPAD+16]
    uint*     B       = (uint*)(row + NPAD + 16);         // [256] (BK+1 used)
    float*    w2m     = (float*)(B + 256);                // [256] ([128]=mean b2)
    float*    mg      = w2m + 256;                        // [NPAD]
    uint*     T       = (uint*)(mg + NPAD);               // [256]
    uint*     counter = T + 256;                          // [16]
    uint*     g16u    = counter + 16;                     // [NPAD*64] (16B aligned)
    u16*      esrc    = (u16*)(g16u + (long)NPAD * 64);   // [E] u16
    uint*     H       = (uint*)(esrc + E);                // [BK*CHN]
    uint*     EB      = H + BK * CHN;                     // [E]

    // K1: histogram chunks + w2m + counter init
    hist_w2m_kernel<<<CHN + 1, 256, 0, stream>>>(dst, H, W2, b2, w2m, counter, E, CHN);
    // K2: per-bucket chunk scan; last block produces B[] and row[N]
    scan_kernel<<<BK, 256, 0, stream>>>(H, T, B, row, counter, CHN, E, N);
    // K3: scatter into bucket regions
    scatter_kernel<<<CHN, 256, 0, stream>>>(src, dst, H, B, EB, E, CHN);
    // K4: bucket sort (196 blocks) || MFMA gemm (391 blocks, 128 rows each)
    sortgemm_kernel<<<BK + GB, 256, 0, stream>>>(EB, B, row, dinv, esrc,
                                                 x, W1, g16u, N, N);
    // K5: gather + lrelu + dot -> mg
    gather_node_kernel<<<(N + 3) / 4, 256, 0, stream>>>(row, esrc, g16u, dinv, b1, w2m, mg, N);
    // K6: scalar aggregate + mean -> out
    out_kernel<<<nblocks, 256, 0, stream>>>(row, esrc, mg, dinv, w2m, out, N);
}

// Round 7
// 201.922 us; speedup vs baseline: 1.8127x; 1.0013x over previous
//
#include <hip/hip_runtime.h>
#include <hip/hip_bf16.h>

// GCN: 2x GCNConv(128->128) + LeakyReLU(0.1) + mean over channels.
// N=50000, E=1600000, D=128, fp32 in/out.
//
// R17: exec-safe rework of R15. R15 FAILED correctness (absmax 1.3e-3):
//   in-loop __shfl(mi, e) read from lanes whose chain had EXITED the while
//   loop -> ds_bpermute from inactive lane returns garbage -> tail edges
//   dropped whenever chains exit unevenly. Fix: hoist ALL shfls into uniform
//   control flow (before divergence): per 64-edge window each lane
//   pre-distributes its chain's <=8 (s,w) pairs into statically-indexed
//   registers sk[0..7]/wk[0..7] (full unroll -> VGPRs, no scratch). The
//   2-deep row pipeline consumes registers only; divergent predicated slots
//   (k < kmax) contain NO cross-lane ops.
// Structure: R9b 6-kernel (196-198us anchor). Cross-block-sync ladder DEAD
//   (R11 grid.sync ~45us; R13 RMW-spin catastrophic). K4 gemm 128 rows/block
//   (R14, neutral-to-slightly-better). K1/K2/K3/K6 R9b verbatim.
// Math (verified R2-R8): h[u]=bf16((x@W1)[u]);  g UNSCALED, dinv per-edge fma:
//   mg[u]=dinv[u]*dot(lrelu(dinv[u]*sum_{n in N(u)+u} dinv[n]*h[n] + b1), mean_j W2[:,j]);
//   out[v]=dinv[v]*(mg[v]+sum mg[nbr]) + mean(b2).

#define N_NODES 50000
#define NPAD 50048
#define D 128
#define BK 196           // node buckets: v>>8
#define CHUNK 4096       // edges per stage-1 block

typedef unsigned int uint;
typedef unsigned short u16;
typedef __attribute__((ext_vector_type(8))) short short8;   // 8 bf16 (4 VGPRs)
typedef __attribute__((ext_vector_type(4))) float floatx4;

__device__ __forceinline__ u16 cvt_bf16(float f) {
    uint u = __float_as_uint(f);
    return (u16)((u + 0x7fffu + ((u >> 16) & 1u)) >> 16);   // RNE
}
__device__ __forceinline__ uint pack_bf2(float a, float b) {
    return (uint)cvt_bf16(a) | ((uint)cvt_bf16(b) << 16);
}

// ---------------- K1: per-chunk bucket histogram  +  w2m  +  counter init ----------------
__global__ void hist_w2m_kernel(const int* __restrict__ dst, uint* __restrict__ H,
                                const float* __restrict__ W2, const float* __restrict__ b2,
                                float* __restrict__ w2m, uint* __restrict__ counter,
                                int E, int CHN) {
    int t = threadIdx.x, c = blockIdx.x;
    if (c < CHN) {                         // histogram chunk
        __shared__ uint h[BK];
        if (t < BK) h[t] = 0;
        __syncthreads();
        int e0 = c * CHUNK;
        for (int i = t; i < CHUNK; i += 256) {
            int e = e0 + i;
            if (e < E) atomicAdd(&h[dst[e] >> 8], 1u);
        }
        __syncthreads();
        if (t < BK) H[t * CHN + c] = h[t]; // bucket-major for column scan
    } else {                               // w2m block
        if (t < 128) {
            float s = 0.f;
            for (int j = 0; j < 128; j++) s += W2[t * 128 + j];
            w2m[t] = s * (1.0f / 128.0f);
        } else if (t == 128) {
            float s = 0.f;
            for (int j = 0; j < 128; j++) s += b2[j];
            w2m[128] = s * (1.0f / 128.0f);
        } else if (t == 129) {
            *counter = 0;                  // for K2 last-block detection
        }
    }
}

// ---------------- K2: per-bucket scan over chunks; last block scans totals ----------------
__global__ void scan_kernel(uint* __restrict__ H, uint* __restrict__ T, uint* __restrict__ B,
                            int* __restrict__ row, uint* __restrict__ counter,
                            int CHN, int E, int N) {
    __shared__ uint s[256];
    __shared__ uint ticket_sh;
    int t = threadIdx.x, b = blockIdx.x;
    uint carry = 0;
    for (int base = 0; base < CHN; base += 256) {
        int idx = base + t;
        uint v = (idx < CHN) ? H[b * CHN + idx] : 0u;
        s[t] = v;
        __syncthreads();
#pragma unroll
        for (int off = 1; off < 256; off <<= 1) {
            uint u = (t >= off) ? s[t - off] : 0u;
            __syncthreads();
            s[t] += u;
            __syncthreads();
        }
        if (idx < CHN) H[b * CHN + idx] = carry + s[t] - v;   // exclusive + carry
        carry += s[255];
        __syncthreads();
    }
    if (t == 0) {
        atomicExch(&T[b], carry);          // device-scope store (crosses XCD L2s)
        __threadfence();
        ticket_sh = atomicAdd(counter, 1);
    }
    __syncthreads();
    if (ticket_sh == (uint)(gridDim.x - 1)) {      // last block: scan bucket totals
        __threadfence();
        uint v = (t < BK) ? atomicAdd(&T[t], 0u) : 0u;   // atomic read (coherent)
        s[t] = v;
        __syncthreads();
#pragma unroll
        for (int off = 1; off < 256; off <<= 1) {
            uint u = (t >= off) ? s[t - off] : 0u;
            __syncthreads();
            s[t] += u;
            __syncthreads();
        }
        if (t < BK) B[t] = s[t] - v;
        if (t == 0) { B[BK] = (uint)E; row[N] = E; }
    }
}

// ---------------- K3: scatter edges into bucket regions (LDS cursors) ----------------
__global__ void scatter_kernel(const int* __restrict__ src, const int* __restrict__ dst,
                               const uint* __restrict__ H, const uint* __restrict__ B,
                               uint* __restrict__ EB, int E, int CHN) {
    __shared__ uint cur[BK];
    int t = threadIdx.x, c = blockIdx.x;
    if (t < BK) cur[t] = B[t] + H[t * CHN + c];
    __syncthreads();
    int e0 = c * CHUNK;
    for (int i = t; i < CHUNK; i += 256) {
        int e = e0 + i;
        if (e < E) {
            int d = dst[e];
            uint slot = atomicAdd(&cur[d >> 8], 1u);
            EB[slot] = ((uint)(d & 255) << 16) | (uint)src[e];
        }
    }
}

// ---------------- K4: bucket_sort (blocks 0..BK-1)  ||  MFMA gemm (blocks BK..) ----------------
// Sort: per-bucket counting sort by dst&255 -> esrc, row, dinv (dense writes).
// Gemm: g16[M,128] = bf16( x @ W1 )  -- UNSCALED (dinv applied per-edge in gather).
// Gemm does 128 rows/block (2 row-groups) to amortize the W1 LDS staging.
#define WT_STRIDE 136
union SortGemmSmem {
    struct { uint cnt[256], s[256], cur[256]; } sort;
    u16 wt[128 * WT_STRIDE];               // 34.8 KB
};
__global__ __launch_bounds__(256) void sortgemm_kernel(
    const uint* __restrict__ EB, const uint* __restrict__ B,
    int* __restrict__ row, float* __restrict__ dinv, u16* __restrict__ esrc,
    const float* __restrict__ A, const float* __restrict__ W,
    uint* __restrict__ G32, int N, int M) {
    __shared__ SortGemmSmem sm;
    int t = threadIdx.x;

    if (blockIdx.x < BK) {                 // ---- bucket sort ----
        int b = blockIdx.x;
        uint base = B[b], ne = B[b + 1] - base;
        sm.sort.cnt[t] = 0;
        __syncthreads();
        for (uint i = t; i < ne; i += 256) atomicAdd(&sm.sort.cnt[EB[base + i] >> 16], 1u);
        __syncthreads();
        uint c = sm.sort.cnt[t];
        sm.sort.s[t] = c;
        __syncthreads();
#pragma unroll
        for (int off = 1; off < 256; off <<= 1) {
            uint u = (t >= off) ? sm.sort.s[t - off] : 0u;
            __syncthreads();
            sm.sort.s[t] += u;
            __syncthreads();
        }
        uint p = sm.sort.s[t] - c;          // exclusive prefix within bucket
        int v = (b << 8) + t;
        if (v < N) {
            row[v] = (int)(base + p);
            dinv[v] = rsqrtf((float)(c + 1u));   // +1 self-loop
        }
        sm.sort.cur[t] = base + p;
        __syncthreads();
        for (uint i = t; i < ne; i += 256) {
            uint u = EB[base + i];
            uint slot = atomicAdd(&sm.sort.cur[u >> 16], 1u);
            esrc[slot] = (u16)(u & 0xffffu);
        }
    } else {                               // ---- MFMA gemm, 128 rows/block ----
        int bid = blockIdx.x - BK;
        for (int i = t; i < 128 * 128; i += 256) {   // stage W1^T as bf16 (once)
            int k = i >> 7, n = i & 127;
            sm.wt[n * WT_STRIDE + k] = cvt_bf16(W[i]);
        }
        __syncthreads();

        int wave = t >> 6, lane = t & 63;
        int m = lane & 15, quad = lane >> 4;

#pragma unroll
        for (int rg = 0; rg < 2; rg++) {
            int rowa = bid * 128 + rg * 64 + wave * 16 + m;
            int rowc = rowa < M ? rowa : M - 1;
            const float* Arow = A + (long)rowc * D;

            short8 afrag[4];
#pragma unroll
            for (int kt = 0; kt < 4; kt++) {
                int k0 = kt * 32 + quad * 8;
                float4 f0 = *(const float4*)(Arow + k0);
                float4 f1 = *(const float4*)(Arow + k0 + 4);
                short8 af;
                af[0] = (short)cvt_bf16(f0.x); af[1] = (short)cvt_bf16(f0.y);
                af[2] = (short)cvt_bf16(f0.z); af[3] = (short)cvt_bf16(f0.w);
                af[4] = (short)cvt_bf16(f1.x); af[5] = (short)cvt_bf16(f1.y);
                af[6] = (short)cvt_bf16(f1.z); af[7] = (short)cvt_bf16(f1.w);
                afrag[kt] = af;
            }

            int orow0 = bid * 128 + rg * 64 + wave * 16;
            for (int n0 = 0; n0 < 128; n0 += 16) {
                floatx4 acc = {0.f, 0.f, 0.f, 0.f};
#pragma unroll
                for (int kt = 0; kt < 4; kt++) {
                    short8 bf = *(const short8*)(sm.wt + (n0 + m) * WT_STRIDE + kt * 32 + quad * 8);
                    acc = __builtin_amdgcn_mfma_f32_16x16x32_bf16(afrag[kt], bf, acc, 0, 0, 0);
                }
#pragma unroll
                for (int r = 0; r < 4; r++) {
                    float val = acc[r];
                    float oth = __shfl_xor(val, 1, 64);      // partner column
                    int orow = orow0 + quad * 4 + r;
                    if (orow < M && (m & 1) == 0)
                        G32[(long)orow * 64 + ((n0 + m) >> 1)] = pack_bf2(val, oth);
                }
            }
        }
    }
}

// ---------------- K5: fused gather(bf16, dinv-fma) + leakyrelu + dot(w2m) ----------------
// One wave/node; 8 chains x 8 lanes; 16 channels per lane.
// R17: per-64-edge window: ONE coalesced esrc preload + ONE gathered dinv,
// then 16 UNCONDITIONAL shfls in uniform flow distribute (s,w) into
// statically-indexed regs sk[0..7]/wk[0..7]; the 2-deep row pipeline
// (predicated slots, no cross-lane ops) consumes registers only.
__global__ __launch_bounds__(256) void gather_node_kernel(
    const int* __restrict__ row, const u16* __restrict__ esrc,
    const uint* __restrict__ g16, const float* __restrict__ dinv,
    const float* __restrict__ b1, const float* __restrict__ w2m,
    float* __restrict__ mg, int N) {
    int wave = threadIdx.x >> 6;
    int lane = threadIdx.x & 63;
    int sub = lane & 7;        // 16-channel slice: uint4 pair 2*sub, 2*sub+1
    int nb = lane >> 3;        // 8 neighbor chains
    int v = blockIdx.x * 4 + wave;
    if (v >= N) return;       // whole wave returns together (v is wave-uniform)

    const uint4* gv = (const uint4*)g16;   // 16 uint4 per 256B row
    float dvv = dinv[v];
    float acc[16];
#pragma unroll
    for (int i = 0; i < 16; i++) acc[i] = 0.f;

#define ACC8(ua, ub, wgt) {                                              \
    uint uu[8] = {(ua).x, (ua).y, (ua).z, (ua).w, (ub).x, (ub).y, (ub).z, (ub).w}; \
    _Pragma("unroll")                                                    \
    for (int i = 0; i < 8; i++) {                                        \
        acc[2*i]   += (wgt) * __uint_as_float(uu[i] << 16);              \
        acc[2*i+1] += (wgt) * __uint_as_float(uu[i] & 0xffff0000u);      \
    } }

    if (nb == 0) {             // self-loop term: dinv[v]*h[v]
        long rb = (long)v * 16 + 2 * sub;
        uint4 ua = gv[rb], ub = gv[rb + 1];
        ACC8(ua, ub, dvv)
    }
    int jb = row[v], je = row[v + 1];
    for (int base = jb; base < je; base += 64) {   // 64-edge windows (uniform loop)
        int navail = je - base; if (navail > 64) navail = 64;
        int mi = 0; float mw = 0.f;
        if (lane < navail) {               // one coalesced u16 load + one gather
            mi = (int)esrc[base + lane];
            mw = dinv[mi];
        }
        // uniform-flow distribution: slot k of chain nb = edge e = nb+8k.
        // ALL lanes active at every shfl (R15 bug fix); lanes >= navail hold
        // mi=0/mw=0 but those slots have k >= kmax and are never accumulated.
        int sk0, sk1, sk2, sk3, sk4, sk5, sk6, sk7;
        float wk0, wk1, wk2, wk3, wk4, wk5, wk6, wk7;
        sk0 = __shfl(mi, nb,      64); wk0 = __shfl(mw, nb,      64);
        sk1 = __shfl(mi, nb + 8,  64); wk1 = __shfl(mw, nb + 8,  64);
        sk2 = __shfl(mi, nb + 16, 64); wk2 = __shfl(mw, nb + 16, 64);
        sk3 = __shfl(mi, nb + 24, 64); wk3 = __shfl(mw, nb + 24, 64);
        sk4 = __shfl(mi, nb + 32, 64); wk4 = __shfl(mw, nb + 32, 64);
        sk5 = __shfl(mi, nb + 40, 64); wk5 = __shfl(mw, nb + 40, 64);
        sk6 = __shfl(mi, nb + 48, 64); wk6 = __shfl(mw, nb + 48, 64);
        sk7 = __shfl(mi, nb + 56, 64); wk7 = __shfl(mw, nb + 56, 64);
        int kmax = (navail > nb) ? ((navail - nb + 7) >> 3) : 0;   // valid slots

        if (kmax > 0) {        // 2-deep pipeline over register slots (no shfl inside)
            long rA = (long)sk0 * 16 + 2 * sub;
            uint4 p0 = gv[rA], p1 = gv[rA + 1];
            float wA = wk0;
#define SLOT(kk, skk, wkk) \
            if (kk < kmax) { \
                long rB = (long)(skk) * 16 + 2 * sub; \
                uint4 q0 = gv[rB], q1 = gv[rB + 1]; \
                ACC8(p0, p1, wA) \
                p0 = q0; p1 = q1; wA = (wkk); \
            }
            SLOT(1, sk1, wk1)
            SLOT(2, sk2, wk2)
            SLOT(3, sk3, wk3)
            SLOT(4, sk4, wk4)
            SLOT(5, sk5, wk5)
            SLOT(6, sk6, wk6)
            SLOT(7, sk7, wk7)
#undef SLOT
            ACC8(p0, p1, wA)   // drain last slot
        }
    }
#undef ACC8

    // reduce the 8 chains
#pragma unroll
    for (int i = 0; i < 16; i++) {
        acc[i] += __shfl_xor(acc[i], 8, 64);
        acc[i] += __shfl_xor(acc[i], 16, 64);
        acc[i] += __shfl_xor(acc[i], 32, 64);
    }

    if (nb == 0) {             // lane sub holds channels 16*sub .. 16*sub+15
        const float4* bp = (const float4*)b1;
        const float4* wp = (const float4*)w2m;
        float s = 0.f;
#pragma unroll
        for (int q4 = 0; q4 < 4; q4++) {
            float4 bb = bp[sub * 4 + q4];
            float4 wm = wp[sub * 4 + q4];
            float t0 = dvv * acc[4*q4 + 0] + bb.x; t0 = t0 >= 0.f ? t0 : 0.1f * t0;
            float t1 = dvv * acc[4*q4 + 1] + bb.y; t1 = t1 >= 0.f ? t1 : 0.1f * t1;
            float t2 = dvv * acc[4*q4 + 2] + bb.z; t2 = t2 >= 0.f ? t2 : 0.1f * t2;
            float t3 = dvv * acc[4*q4 + 3] + bb.w; t3 = t3 >= 0.f ? t3 : 0.1f * t3;
            s += t0 * wm.x + t1 * wm.y + t2 * wm.z + t3 * wm.w;
        }
        s += __shfl_xor(s, 1, 64);
        s += __shfl_xor(s, 2, 64);
        s += __shfl_xor(s, 4, 64);
        if (sub == 0) mg[v] = dvv * s;
    }
}

// ---------------- K6: scalar aggregate for conv2 + mean ----------------
__global__ void out_kernel(const int* __restrict__ row, const u16* __restrict__ esrc,
                           const float* __restrict__ mg, const float* __restrict__ dinv,
                           const float* __restrict__ w2m, float* __restrict__ out, int N) {
    int v = blockIdx.x * blockDim.x + threadIdx.x;
    if (v >= N) return;
    float acc = mg[v];
    int jb = row[v], je = row[v + 1];
    int j = jb;
    for (; j + 8 <= je; j += 8) {
        acc += mg[esrc[j]] + mg[esrc[j + 1]] + mg[esrc[j + 2]] + mg[esrc[j + 3]] +
               mg[esrc[j + 4]] + mg[esrc[j + 5]] + mg[esrc[j + 6]] + mg[esrc[j + 7]];
    }
    for (; j < je; j++) acc += mg[esrc[j]];
    out[v] = dinv[v] * acc + w2m[128];
}

extern "C" void kernel_launch(void* const* d_in, const int* in_sizes, int n_in,
                              void* d_out, int out_size, void* d_ws, size_t ws_size,
                              hipStream_t stream) {
    const float* x  = (const float*)d_in[0];
    const int* ei   = (const int*)d_in[1];
    const float* W1 = (const float*)d_in[2];
    const float* b1 = (const float*)d_in[3];
    const float* W2 = (const float*)d_in[4];
    const float* b2 = (const float*)d_in[5];
    float* out = (float*)d_out;

    const int N = N_NODES;
    const int E = in_sizes[1] / 2;
    const int* src = ei;
    const int* dst = ei + E;
    const int CHN = (E + CHUNK - 1) / CHUNK;   // 391
    const int nblocks = (N + 255) / 256;       // 196
    const int GB = (N + 127) / 128;            // 391 gemm blocks (128 rows each)

    // workspace (4B units). EB is NOT aliased with g16 (sort runs || gemm in K4).
    float*    dinv    = (float*)d_ws;                     // [NPAD]
    int*      row     = (int*)(dinv + NPAD);              // [NPAD+16]
    uint*     B       = (uint*)(row + NPAD + 16);         // [256] (BK+1 used)
    float*    w2m     = (float*)(B + 256);                // [256] ([128]=mean b2)
    float*    mg      = w2m + 256;                        // [NPAD]
    uint*     T       = (uint*)(mg + NPAD);               // [256]
    uint*     counter = T + 256;                          // [16]
    uint*     g16u    = counter + 16;                     // [NPAD*64] (16B aligned)
    u16*      esrc    = (u16*)(g16u + (long)NPAD * 64);   // [E] u16
    uint*     H       = (uint*)(esrc + E);                // [BK*CHN]
    uint*     EB      = H + BK * CHN;                     // [E]

    // K1: histogram chunks + w2m + counter init
    hist_w2m_kernel<<<CHN + 1, 256, 0, stream>>>(dst, H, W2, b2, w2m, counter, E, CHN);
    // K2: per-bucket chunk scan; last block produces B[] and row[N]
    scan_kernel<<<BK, 256, 0, stream>>>(H, T, B, row, counter, CHN, E, N);
    // K3: scatter into bucket regions
    scatter_kernel<<<CHN, 256, 0, stream>>>(src, dst, H, B, EB, E, CHN);
    // K4: bucket sort (196 blocks) || MFMA gemm (391 blocks, 128 rows each)
    sortgemm_kernel<<<BK + GB, 256, 0, stream>>>(EB, B, row, dinv, esrc,
                                                 x, W1, g16u, N, N);
    // K5: gather + lrelu + dot -> mg
    gather_node_kernel<<<(N + 3) / 4, 256, 0, stream>>>(row, esrc, g16u, dinv, b1, w2m, mg, N);
    // K6: scalar aggregate + mean -> out
    out_kernel<<<nblocks, 256, 0, stream>>>(row, esrc, mg, dinv, w2m, out, N);
}